// Round 4
// baseline (241.441 us; speedup 1.0000x reference)
//
#include <hip/hip_runtime.h>
#include <hip/hip_bf16.h>

// STDP: delta_w[q,p] = 4*w*(1-w) * (A/B) * sum_k AT[q][k]*BT[p][k]
//   AT[q][ b*128+t        ] = post_spikes[b][t][q]
//   AT[q][ 2048 + b*128+t ] = post_trace [b][t][q]
//   BT[p][ b*128+t        ] = pre_trace  [b][t][p]
//   BT[p][ 2048 + b*128+t ] = -pre_spikes[b][t][p]

typedef __attribute__((ext_vector_type(8))) short bf16x8;
typedef __attribute__((ext_vector_type(4))) float f32x4;

#define GN 2048
#define GK 4096
#define A_SCALE (0.01f / 16.0f)

// ---------------------------------------------------------------------------
// Kernel 1: trace + transpose, LDS-cooperative (unchanged, ~18us).
// grid (32, 16, 2), block 256 (4 waves). z=0: post->AT, z=1: pre->BT
// ---------------------------------------------------------------------------
__global__ __launch_bounds__(256) void trace_kernel(
    const float* __restrict__ pre,
    const float* __restrict__ post,
    const int* __restrict__ dtp,
    __hip_bfloat16* __restrict__ AT,
    __hip_bfloat16* __restrict__ BT)
{
    __shared__ char smem[128 * 65 * 4 + 128 * 65 * 2];  // 49920 B -> 3 blocks/CU
    float* fbuf = (float*)smem;                                     // [128][65] fp32
    __hip_bfloat16* spk = (__hip_bfloat16*)(smem + 128 * 65 * 4);   // [128][65] bf16
    __hip_bfloat16* trb = (__hip_bfloat16*)smem;                    // [128][65] overlay

    const int tid = threadIdx.x;
    const int w   = tid >> 6;    // wave 0..3
    const int l   = tid & 63;
    const int n0  = blockIdx.x * 64;
    const int b   = blockIdx.y;
    const int a   = blockIdx.z;

    int di = dtp[0];
    float dtf = (di > 0 && di < 1000000) ? (float)di : *(const float*)dtp;
    const float decay = __expf(-dtf / 20.0f);

    const float* src = (a == 0) ? post : pre;
    const float  sgn = (a == 0) ? 1.0f : -1.0f;  // BT spikes carry the minus sign

    // phase 1: cooperative load. t = i*4 + w, n = n0 + l.
    #pragma unroll 8
    for (int i = 0; i < 32; ++i) {
        const int t = i * 4 + w;
        float v = src[((size_t)b * 128 + t) * GN + n0 + l];
        fbuf[t * 65 + l] = v;
        spk[t * 65 + l]  = __float2bfloat16(v * sgn);
    }
    __syncthreads();

    // phase 2: scan. trace[0]=0; trace[t] = decay*trace[t-1] + s[t] (t>=1).
    const int t0 = 32 * w;
    float carry = 0.0f;
    #pragma unroll 8
    for (int t = 1; t < t0; ++t)
        carry = decay * carry + fbuf[t * 65 + l];
    float seg[32];
    #pragma unroll
    for (int j = 0; j < 32; ++j) {
        const int t = t0 + j;
        if (t >= 1) carry = decay * carry + fbuf[t * 65 + l];
        seg[j] = carry;  // t=0 -> 0
    }
    __syncthreads();   // all waves done reading fbuf

    // phase 3: trace bf16 into overlay
    #pragma unroll
    for (int j = 0; j < 32; ++j)
        trb[(t0 + j) * 65 + l] = __float2bfloat16(seg[j]);
    __syncthreads();

    // phase 4: 2048 16B-chunks/block, 8 per thread, lane-consecutive.
    const __hip_bfloat16* s1 = (a == 0) ? spk : trb;  // first k-half
    const __hip_bfloat16* s2 = (a == 0) ? trb : spk;  // second k-half
    __hip_bfloat16* dst = (a == 0) ? AT : BT;

    #pragma unroll
    for (int j = 0; j < 8; ++j) {
        const int c   = tid + 256 * j;
        const int n   = c >> 5;          // 0..63
        const int sec = (c >> 4) & 1;    // 0: first half, 1: second half
        const int tc  = c & 15;          // 16B chunk within 128 t
        const __hip_bfloat16* s = sec ? s2 : s1;
        unsigned int vv[8];
        #pragma unroll
        for (int i = 0; i < 8; ++i)
            vv[i] = *(const unsigned short*)&s[(8 * tc + i) * 65 + n];
        uint4 pk;
        pk.x = vv[0] | (vv[1] << 16);
        pk.y = vv[2] | (vv[3] << 16);
        pk.z = vv[4] | (vv[5] << 16);
        pk.w = vv[6] | (vv[7] << 16);
        const size_t off = (size_t)(n0 + n) * GK + (sec ? (2048 + b * 128) : (b * 128)) + tc * 8;
        *(uint4*)(dst + off) = pk;
    }
}

// ---------------------------------------------------------------------------
// Kernel 2: C = AT * BT^T, 128x128 tile, BK=64, double-buffered LDS,
// staging via global->VGPR->ds_write (NOT global_load_lds!): the barrier then
// only drains lgkmcnt (the just-issued ds_writes, cheap); the plain global
// loads for tile t+1 stay IN FLIGHT across the barrier and the compute phase
// (~1000 cyc), so their latency is fully hidden even at 1 block/CU.
// The vmcnt wait lands at the ds_write consuming the registers, one full
// iteration after issue. XOR k-chunk swizzle applied on the ds_write side
// (per-lane scatter is free now); global loads are perfectly linear.
// grid (16,16) = 256 blocks, 256 threads, 4 waves of 64x64.
// ---------------------------------------------------------------------------
__global__ __launch_bounds__(256) void stdp_gemm(
    const __hip_bfloat16* __restrict__ AT,
    const __hip_bfloat16* __restrict__ BT,
    const float* __restrict__ W,
    float* __restrict__ out)
{
    __shared__ alignas(16) __hip_bfloat16 As[2][128 * 64];
    __shared__ alignas(16) __hip_bfloat16 Bs[2][128 * 64];

    const int tid  = threadIdx.x;
    const int lane = tid & 63;
    const int wv   = tid >> 6;          // wave 0..3
    const int wm   = (wv >> 1) * 64;
    const int wn   = (wv & 1) * 64;
    const int RM   = blockIdx.y * 128;  // q base
    const int CN   = blockIdx.x * 128;  // p base
    const int l15  = lane & 15;
    const int quad = lane >> 4;

    f32x4 acc[4][4] = {};

    // per-thread staging: 4 A-chunks + 4 B-chunks of 16B. chunk c = tid + 256j:
    // global (row = c>>3, kchunk = c&7) read linearly (coalesced);
    // LDS slot = kchunk ^ (row&7)  (XOR swizzle, matches compute-side reads).
    uint4 ra[4], rb[4], ra2[4], rb2[4];

    auto gload = [&](uint4* a, uint4* b, int k0) {
        #pragma unroll
        for (int j = 0; j < 4; ++j) {
            const int c   = tid + 256 * j;
            const int row = c >> 3;
            const int kc  = c & 7;
            a[j] = *(const uint4*)(AT + (size_t)(RM + row) * GK + k0 + kc * 8);
            b[j] = *(const uint4*)(BT + (size_t)(CN + row) * GK + k0 + kc * 8);
        }
    };
    auto swrite = [&](int buf, const uint4* a, const uint4* b) {
        #pragma unroll
        for (int j = 0; j < 4; ++j) {
            const int c    = tid + 256 * j;
            const int row  = c >> 3;
            const int slot = (c & 7) ^ (row & 7);
            *(uint4*)(&As[buf][row * 64 + slot * 8]) = a[j];
            *(uint4*)(&Bs[buf][row * 64 + slot * 8]) = b[j];
        }
    };
    auto compute = [&](int buf) {
        #pragma unroll
        for (int kk = 0; kk < 64; kk += 32) {
            const int jg = (kk >> 3) + quad;
            bf16x8 af[4], bfr[4];
            #pragma unroll
            for (int i = 0; i < 4; ++i) {
                const int mr = wm + i * 16 + l15;
                af[i]  = *(const bf16x8*)(&As[buf][mr * 64 + ((jg ^ (mr & 7)) * 8)]);
                const int nr = wn + i * 16 + l15;
                bfr[i] = *(const bf16x8*)(&Bs[buf][nr * 64 + ((jg ^ (nr & 7)) * 8)]);
            }
            #pragma unroll
            for (int i = 0; i < 4; ++i)
                #pragma unroll
                for (int j = 0; j < 4; ++j)
                    acc[i][j] = __builtin_amdgcn_mfma_f32_16x16x32_bf16(
                        af[i], bfr[j], acc[i][j], 0, 0, 0);
        }
    };

    gload(ra, rb, 0);
    for (int t = 0; t < 64; t += 2) {
        // even iter -> buf 0
        swrite(0, ra, rb);                       // vmcnt wait for ra/rb lands here
        gload(ra2, rb2, (t + 1) * 64);           // t+1 <= 63 always; fly across barrier
        __syncthreads();                         // lgkm drain only (no LDS-bound vmem)
        compute(0);
        // odd iter -> buf 1
        swrite(1, ra2, rb2);
        if (t + 2 < 64) gload(ra, rb, (t + 2) * 64);
        __syncthreads();
        compute(1);
    }

    // epilogue: C/D layout col = lane&15, row = quad*4 + reg (m89-verified)
    #pragma unroll
    for (int i = 0; i < 4; ++i) {
        #pragma unroll
        for (int r = 0; r < 4; ++r) {
            const int q = RM + wm + i * 16 + quad * 4 + r;
            #pragma unroll
            for (int j = 0; j < 4; ++j) {
                const int p = CN + wn + j * 16 + l15;
                const float w  = W[(size_t)q * GN + p];
                const float wf = 4.0f * w * (1.0f - w);
                out[(size_t)q * GN + p] = wf * A_SCALE * acc[i][j][r];
            }
        }
    }
}

extern "C" void kernel_launch(void* const* d_in, const int* in_sizes, int n_in,
                              void* d_out, int out_size, void* d_ws, size_t ws_size,
                              hipStream_t stream) {
    const float* W    = (const float*)d_in[0];  // [2048][2048]
    const float* pre  = (const float*)d_in[1];  // [16][128][2048]
    const float* post = (const float*)d_in[2];  // [16][128][2048]
    const int*   dt   = (const int*)d_in[3];
    float* out = (float*)d_out;

    __hip_bfloat16* AT = (__hip_bfloat16*)d_ws;            // 16 MB
    __hip_bfloat16* BT = AT + (size_t)GN * GK;             // +16 MB

    trace_kernel<<<dim3(32, 16, 2), 256, 0, stream>>>(pre, post, dt, AT, BT);
    stdp_gemm<<<dim3(16, 16), 256, 0, stream>>>(AT, BT, W, out);
}

// Round 5
// 150.225 us; speedup vs baseline: 1.6072x; 1.6072x over previous
//
#include <hip/hip_runtime.h>
#include <hip/hip_bf16.h>

// STDP: delta_w[q,p] = 4*w*(1-w) * (A/B) * sum_k AT[q][k]*BT[p][k]
//   AT[q][ b*128+t        ] = post_spikes[b][t][q]
//   AT[q][ 2048 + b*128+t ] = post_trace [b][t][q]
//   BT[p][ b*128+t        ] = pre_trace  [b][t][p]
//   BT[p][ 2048 + b*128+t ] = -pre_spikes[b][t][p]

typedef __attribute__((ext_vector_type(8))) short bf16x8;
typedef __attribute__((ext_vector_type(4))) float f32x4;

#define GN 2048
#define GK 4096
#define A_SCALE (0.01f / 16.0f)

#define GLOAD_LDS16(gp, lp) \
    __builtin_amdgcn_global_load_lds((const __attribute__((address_space(1))) void*)(gp), \
                                     (__attribute__((address_space(3))) void*)(lp), 16, 0, 0)

// ---------------------------------------------------------------------------
// Kernel 1: trace + transpose, LDS-cooperative (unchanged).
// grid (32, 16, 2), block 256 (4 waves). z=0: post->AT, z=1: pre->BT
// ---------------------------------------------------------------------------
__global__ __launch_bounds__(256) void trace_kernel(
    const float* __restrict__ pre,
    const float* __restrict__ post,
    const int* __restrict__ dtp,
    __hip_bfloat16* __restrict__ AT,
    __hip_bfloat16* __restrict__ BT)
{
    __shared__ char smem[128 * 65 * 4 + 128 * 65 * 2];  // 49920 B -> 3 blocks/CU
    float* fbuf = (float*)smem;                                     // [128][65] fp32
    __hip_bfloat16* spk = (__hip_bfloat16*)(smem + 128 * 65 * 4);   // [128][65] bf16
    __hip_bfloat16* trb = (__hip_bfloat16*)smem;                    // [128][65] overlay

    const int tid = threadIdx.x;
    const int w   = tid >> 6;    // wave 0..3
    const int l   = tid & 63;
    const int n0  = blockIdx.x * 64;
    const int b   = blockIdx.y;
    const int a   = blockIdx.z;

    int di = dtp[0];
    float dtf = (di > 0 && di < 1000000) ? (float)di : *(const float*)dtp;
    const float decay = __expf(-dtf / 20.0f);

    const float* src = (a == 0) ? post : pre;
    const float  sgn = (a == 0) ? 1.0f : -1.0f;  // BT spikes carry the minus sign

    #pragma unroll 8
    for (int i = 0; i < 32; ++i) {
        const int t = i * 4 + w;
        float v = src[((size_t)b * 128 + t) * GN + n0 + l];
        fbuf[t * 65 + l] = v;
        spk[t * 65 + l]  = __float2bfloat16(v * sgn);
    }
    __syncthreads();

    const int t0 = 32 * w;
    float carry = 0.0f;
    #pragma unroll 8
    for (int t = 1; t < t0; ++t)
        carry = decay * carry + fbuf[t * 65 + l];
    float seg[32];
    #pragma unroll
    for (int j = 0; j < 32; ++j) {
        const int t = t0 + j;
        if (t >= 1) carry = decay * carry + fbuf[t * 65 + l];
        seg[j] = carry;  // t=0 -> 0
    }
    __syncthreads();

    #pragma unroll
    for (int j = 0; j < 32; ++j)
        trb[(t0 + j) * 65 + l] = __float2bfloat16(seg[j]);
    __syncthreads();

    const __hip_bfloat16* s1 = (a == 0) ? spk : trb;  // first k-half
    const __hip_bfloat16* s2 = (a == 0) ? trb : spk;  // second k-half
    __hip_bfloat16* dst = (a == 0) ? AT : BT;

    #pragma unroll
    for (int j = 0; j < 8; ++j) {
        const int c   = tid + 256 * j;
        const int n   = c >> 5;
        const int sec = (c >> 4) & 1;
        const int tc  = c & 15;
        const __hip_bfloat16* s = sec ? s2 : s1;
        unsigned int vv[8];
        #pragma unroll
        for (int i = 0; i < 8; ++i)
            vv[i] = *(const unsigned short*)&s[(8 * tc + i) * 65 + n];
        uint4 pk;
        pk.x = vv[0] | (vv[1] << 16);
        pk.y = vv[2] | (vv[3] << 16);
        pk.z = vv[4] | (vv[5] << 16);
        pk.w = vv[6] | (vv[7] << 16);
        const size_t off = (size_t)(n0 + n) * GK + (sec ? (2048 + b * 128) : (b * 128)) + tc * 8;
        *(uint4*)(dst + off) = pk;
    }
}

// ---------------------------------------------------------------------------
// Kernel 2: C = AT * BT^T.  128x64 tile, BK=64, R1's proven single-buffer
// global_load_lds structure.  Split-K via blockIdx.z (klen = GK/zsplit):
// grid (32,16,2) = 1024 blocks = 4 blocks/CU -> the m114 cross-block overlap
// fills each block's barrier drain (m102: 1->4 blocks/CU = 320->833 TF).
// z=0 writes raw partial to out0 (=d_out), z=1 to out1 (ws scratch).
// do_epi!=0 (fallback single-pass) applies the softbound epilogue directly.
// 4 waves of 64x32: acc[4][2], 12 ds_read_b128 + 16 MFMA per BK-iter.
// LDS 24 KB, VGPR ~90 -> fits 4 blocks/CU at 16 waves/CU.
// ---------------------------------------------------------------------------
__global__ __launch_bounds__(256) void stdp_gemm(
    const __hip_bfloat16* __restrict__ AT,
    const __hip_bfloat16* __restrict__ BT,
    const float* __restrict__ W,
    float* __restrict__ out0,
    float* __restrict__ out1,
    int klen, int do_epi)
{
    __shared__ alignas(16) __hip_bfloat16 As[128 * 64];
    __shared__ alignas(16) __hip_bfloat16 Bs[64 * 64];

    const int tid  = threadIdx.x;
    const int lane = tid & 63;
    const int wv   = tid >> 6;          // wave 0..3
    const int wm   = (wv >> 1) * 64;    // {0,64}
    const int wn   = (wv & 1) * 32;     // {0,32}
    const int RM   = blockIdx.y * 128;  // q base
    const int CN   = blockIdx.x * 64;   // p base
    const int K0   = blockIdx.z * klen;
    const int l15  = lane & 15;
    const int quad = lane >> 4;

    f32x4 acc[4][2] = {};

    for (int k0 = K0; k0 < K0 + klen; k0 += 64) {
        __syncthreads();  // previous iter's ds_reads done before overwrite
        // stage A: 128 rows x 64 k = 16 KB = 16 wave-instr (4 per wave)
        #pragma unroll
        for (int it = 0; it < 4; ++it) {
            const int cbase = it * 256 + wv * 64;      // wave-uniform chunk base
            const int c     = cbase + lane;            // 16B chunk id 0..1023
            const int row   = c >> 3;                  // 0..127
            const int kc    = (c & 7) ^ (row & 7);     // XOR swizzle (self-inverse)
            GLOAD_LDS16(AT + (size_t)(RM + row) * GK + k0 + kc * 8, As + (size_t)cbase * 8);
        }
        // stage B: 64 rows x 64 k = 8 KB = 8 wave-instr (2 per wave)
        #pragma unroll
        for (int it = 0; it < 2; ++it) {
            const int cbase = it * 256 + wv * 64;
            const int c     = cbase + lane;            // 0..511
            const int row   = c >> 3;                  // 0..63
            const int kc    = (c & 7) ^ (row & 7);
            GLOAD_LDS16(BT + (size_t)(CN + row) * GK + k0 + kc * 8, Bs + (size_t)cbase * 8);
        }
        __syncthreads();  // vmcnt(0) drain: staged data visible

        #pragma unroll
        for (int kk = 0; kk < 64; kk += 32) {
            const int jg = (kk >> 3) + quad;  // k-chunk 0..3 / 4..7
            bf16x8 af[4], bfr[2];
            #pragma unroll
            for (int i = 0; i < 4; ++i) {
                const int mr = wm + i * 16 + l15;
                af[i] = *(const bf16x8*)(As + mr * 64 + ((jg ^ (mr & 7)) * 8));
            }
            #pragma unroll
            for (int j = 0; j < 2; ++j) {
                const int nr = wn + j * 16 + l15;
                bfr[j] = *(const bf16x8*)(Bs + nr * 64 + ((jg ^ (nr & 7)) * 8));
            }
            #pragma unroll
            for (int i = 0; i < 4; ++i)
                #pragma unroll
                for (int j = 0; j < 2; ++j)
                    acc[i][j] = __builtin_amdgcn_mfma_f32_16x16x32_bf16(
                        af[i], bfr[j], acc[i][j], 0, 0, 0);
        }
    }

    // C/D layout: col = lane&15, row = quad*4 + reg (m89-verified)
    float* outp = (blockIdx.z == 0) ? out0 : out1;
    #pragma unroll
    for (int i = 0; i < 4; ++i) {
        #pragma unroll
        for (int r = 0; r < 4; ++r) {
            const int q = RM + wm + i * 16 + quad * 4 + r;
            #pragma unroll
            for (int j = 0; j < 2; ++j) {
                const int p = CN + wn + j * 16 + l15;
                float v = acc[i][j][r];
                if (do_epi) {
                    const float w = W[(size_t)q * GN + p];
                    v *= 4.0f * w * (1.0f - w) * A_SCALE;
                }
                outp[(size_t)q * GN + p] = v;
            }
        }
    }
}

// ---------------------------------------------------------------------------
// Kernel 3: combine split-K partials + softbound epilogue.
// out = 4*w*(1-w) * A_SCALE * (P0 + P1); P0 aliases out (raw partial).
// grid 4096 x 256, float4 -> 64 MB traffic ~ 12 us.
// ---------------------------------------------------------------------------
__global__ __launch_bounds__(256) void combine_kernel(
    const float4* __restrict__ W,
    const float4* __restrict__ P1,
    float4* __restrict__ out)
{
    const size_t i = (size_t)blockIdx.x * 256 + threadIdx.x;
    float4 w = W[i];
    float4 a = out[i];   // raw partial z=0
    float4 b = P1[i];    // raw partial z=1
    float4 o;
    o.x = 4.0f * w.x * (1.0f - w.x) * A_SCALE * (a.x + b.x);
    o.y = 4.0f * w.y * (1.0f - w.y) * A_SCALE * (a.y + b.y);
    o.z = 4.0f * w.z * (1.0f - w.z) * A_SCALE * (a.z + b.z);
    o.w = 4.0f * w.w * (1.0f - w.w) * A_SCALE * (a.w + b.w);
    out[i] = o;
}

extern "C" void kernel_launch(void* const* d_in, const int* in_sizes, int n_in,
                              void* d_out, int out_size, void* d_ws, size_t ws_size,
                              hipStream_t stream) {
    const float* W    = (const float*)d_in[0];  // [2048][2048]
    const float* pre  = (const float*)d_in[1];  // [16][128][2048]
    const float* post = (const float*)d_in[2];  // [16][128][2048]
    const int*   dt   = (const int*)d_in[3];
    float* out = (float*)d_out;

    __hip_bfloat16* AT = (__hip_bfloat16*)d_ws;            // 16 MB
    __hip_bfloat16* BT = AT + (size_t)GN * GK;             // +16 MB
    float* P1 = (float*)((char*)d_ws + (size_t)32 * 1024 * 1024);  // +16 MB

    trace_kernel<<<dim3(32, 16, 2), 256, 0, stream>>>(pre, post, dt, AT, BT);

    if (ws_size >= (size_t)48 * 1024 * 1024) {
        // split-K=2: 1024 blocks = 4 blocks/CU; combine applies epilogue
        stdp_gemm<<<dim3(32, 16, 2), 256, 0, stream>>>(AT, BT, W, out, P1, GK / 2, 0);
        combine_kernel<<<4096, 256, 0, stream>>>((const float4*)W, (const float4*)P1,
                                                 (float4*)out);
    } else {
        // fallback: single-pass, epilogue fused (R1 behavior)
        stdp_gemm<<<dim3(32, 16, 1), 256, 0, stream>>>(AT, BT, W, out, nullptr, GK, 1);
    }
}

// Round 6
// 128.666 us; speedup vs baseline: 1.8765x; 1.1676x over previous
//
#include <hip/hip_runtime.h>
#include <hip/hip_bf16.h>

// STDP via the antisymmetric-kernel identity:
//   ltp+ltd = A_SCALE * sum_{b,t} post_s[b,t,q] * ( pre_tr[b,t,p] - pre_rt[b,t,p] )
// where pre_tr = causal decay scan (trace), pre_rt = ANTI-causal decay scan:
//   rt[t] = decay*rt[t+1] + s[t]  (t>=1), rt[0] = 0
// Proof: tr = D s with D[t,t'] = decay^(t-t') [1<=t'<=t];
//   C = sum_b post^T D pre - (D post)^T pre = sum_b post^T (D - D^T) pre,
//   and (D^T s)[t] = [t>=1] * sum_{t'>=t} decay^(t'-t) s[t'] = rt.
// This halves the main GEMM: K = 2048 instead of 4096.
//   AT[q][b*128+t] = post_spikes[b][t][q]        (bf16)
//   BT[p][b*128+t] = pre_tr - pre_rt  (fp32 scans, one bf16 round)

typedef __attribute__((ext_vector_type(8))) short bf16x8;
typedef __attribute__((ext_vector_type(4))) float f32x4;

#define GN 2048
#define KTOT 2048
#define A_SCALE (0.01f / 16.0f)

#define GLOAD_LDS16(gp, lp) \
    __builtin_amdgcn_global_load_lds((const __attribute__((address_space(1))) void*)(gp), \
                                     (__attribute__((address_space(3))) void*)(lp), 16, 0, 0)

// ---------------------------------------------------------------------------
// Kernel 1: transpose (+ double scan for the pre side).
// grid (32, 16, 2), block 256 (4 waves). z=0: post -> AT (spikes only),
// z=1: pre -> BT (Z = forward trace - backward trace, fp32).
// LDS 49920 B -> 3 blocks/CU.
// ---------------------------------------------------------------------------
__global__ __launch_bounds__(256) void trace_kernel(
    const float* __restrict__ pre,
    const float* __restrict__ post,
    const int* __restrict__ dtp,
    __hip_bfloat16* __restrict__ AT,
    __hip_bfloat16* __restrict__ BT)
{
    __shared__ float fbuf[128 * 65];                 // 33280 B, t-major fp32
    __shared__ __hip_bfloat16 zbuf[128 * 65];        // 16640 B, t-major bf16

    const int tid = threadIdx.x;
    const int w   = tid >> 6;    // wave 0..3
    const int l   = tid & 63;
    const int n0  = blockIdx.x * 64;
    const int b   = blockIdx.y;
    const int a   = blockIdx.z;  // 0: post->AT, 1: pre->BT

    int di = dtp[0];
    float dtf = (di > 0 && di < 1000000) ? (float)di : *(const float*)dtp;
    const float decay = __expf(-dtf / 20.0f);

    if (a == 0) {
        // spikes only: straight bf16 into zbuf
        #pragma unroll 8
        for (int i = 0; i < 32; ++i) {
            const int t = i * 4 + w;
            float v = post[((size_t)b * 128 + t) * GN + n0 + l];
            zbuf[t * 65 + l] = __float2bfloat16(v);
        }
        __syncthreads();
    } else {
        #pragma unroll 8
        for (int i = 0; i < 32; ++i) {
            const int t = i * 4 + w;
            fbuf[t * 65 + l] = pre[((size_t)b * 128 + t) * GN + n0 + l];
        }
        __syncthreads();

        const int t0 = 32 * w;   // this wave's t segment [t0, t0+32)
        // forward scan: tr[t] = decay*tr[t-1] + s[t] (t>=1), tr[0]=0
        float carry = 0.0f;
        #pragma unroll 8
        for (int t = 1; t < t0; ++t)
            carry = decay * carry + fbuf[t * 65 + l];
        float z[32];
        #pragma unroll
        for (int j = 0; j < 32; ++j) {
            const int t = t0 + j;
            if (t >= 1) carry = decay * carry + fbuf[t * 65 + l];
            z[j] = carry;                     // tr (t=0 -> 0)
        }
        // backward scan: rt[t] = decay*rt[t+1] + s[t]; used only for t>=1
        float bc = 0.0f;
        #pragma unroll 8
        for (int t = 127; t >= t0 + 32; --t)
            bc = decay * bc + fbuf[t * 65 + l];
        #pragma unroll
        for (int j = 31; j >= 0; --j) {
            const int t = t0 + j;
            bc = decay * bc + fbuf[t * 65 + l];
            if (t >= 1) z[j] -= bc;           // Z = tr - rt   (Z[0] = 0)
        }
        #pragma unroll
        for (int j = 0; j < 32; ++j)
            zbuf[(t0 + j) * 65 + l] = __float2bfloat16(z[j]);
        __syncthreads();
    }

    // transpose-write: 1024 16B-chunks/block, 4 per thread.
    __hip_bfloat16* dst = (a == 0) ? AT : BT;
    #pragma unroll
    for (int j = 0; j < 4; ++j) {
        const int c  = tid + 256 * j;   // 0..1023
        const int n  = c >> 4;          // 0..63
        const int tc = c & 15;          // 8-t chunk
        unsigned int vv[8];
        #pragma unroll
        for (int i = 0; i < 8; ++i)
            vv[i] = *(const unsigned short*)&zbuf[(8 * tc + i) * 65 + n];
        uint4 pk;
        pk.x = vv[0] | (vv[1] << 16);
        pk.y = vv[2] | (vv[3] << 16);
        pk.z = vv[4] | (vv[5] << 16);
        pk.w = vv[6] | (vv[7] << 16);
        *(uint4*)(dst + (size_t)(n0 + n) * KTOT + b * 128 + tc * 8) = pk;
    }
}

// ---------------------------------------------------------------------------
// Kernel 2: C = AT * BT^T over K=2048.  R5-proven structure: 128x64 tile,
// BK=64, single-buffer global_load_lds, split-K=2 via blockIdx.z ->
// grid (32,16,2) = 1024 blocks = 4 blocks/CU (m114 cross-block overlap fills
// the barrier drain).  z=0 -> out0 raw partial, z=1 -> out1.
// 4 waves of 64x32: acc[4][2].  LDS 24 KB, VGPR ~52 -> 16 waves/CU.
// ---------------------------------------------------------------------------
__global__ __launch_bounds__(256) void stdp_gemm(
    const __hip_bfloat16* __restrict__ AT,
    const __hip_bfloat16* __restrict__ BT,
    float* __restrict__ out0,
    float* __restrict__ out1,
    int klen)
{
    __shared__ alignas(16) __hip_bfloat16 As[128 * 64];
    __shared__ alignas(16) __hip_bfloat16 Bs[64 * 64];

    const int tid  = threadIdx.x;
    const int lane = tid & 63;
    const int wv   = tid >> 6;          // wave 0..3
    const int wm   = (wv >> 1) * 64;    // {0,64}
    const int wn   = (wv & 1) * 32;     // {0,32}
    const int RM   = blockIdx.y * 128;  // q base
    const int CN   = blockIdx.x * 64;   // p base
    const int K0   = blockIdx.z * klen;
    const int l15  = lane & 15;
    const int quad = lane >> 4;

    f32x4 acc[4][2] = {};

    for (int k0 = K0; k0 < K0 + klen; k0 += 64) {
        __syncthreads();  // previous iter's ds_reads done before overwrite
        #pragma unroll
        for (int it = 0; it < 4; ++it) {
            const int cbase = it * 256 + wv * 64;      // wave-uniform chunk base
            const int c     = cbase + lane;            // 16B chunk id 0..1023
            const int row   = c >> 3;                  // 0..127
            const int kc    = (c & 7) ^ (row & 7);     // XOR swizzle (self-inverse)
            GLOAD_LDS16(AT + (size_t)(RM + row) * KTOT + k0 + kc * 8, As + (size_t)cbase * 8);
        }
        #pragma unroll
        for (int it = 0; it < 2; ++it) {
            const int cbase = it * 256 + wv * 64;
            const int c     = cbase + lane;            // 0..511
            const int row   = c >> 3;                  // 0..63
            const int kc    = (c & 7) ^ (row & 7);
            GLOAD_LDS16(BT + (size_t)(CN + row) * KTOT + k0 + kc * 8, Bs + (size_t)cbase * 8);
        }
        __syncthreads();  // vmcnt(0) drain: staged data visible

        #pragma unroll
        for (int kk = 0; kk < 64; kk += 32) {
            const int jg = (kk >> 3) + quad;
            bf16x8 af[4], bfr[2];
            #pragma unroll
            for (int i = 0; i < 4; ++i) {
                const int mr = wm + i * 16 + l15;
                af[i] = *(const bf16x8*)(As + mr * 64 + ((jg ^ (mr & 7)) * 8));
            }
            #pragma unroll
            for (int j = 0; j < 2; ++j) {
                const int nr = wn + j * 16 + l15;
                bfr[j] = *(const bf16x8*)(Bs + nr * 64 + ((jg ^ (nr & 7)) * 8));
            }
            #pragma unroll
            for (int i = 0; i < 4; ++i)
                #pragma unroll
                for (int j = 0; j < 2; ++j)
                    acc[i][j] = __builtin_amdgcn_mfma_f32_16x16x32_bf16(
                        af[i], bfr[j], acc[i][j], 0, 0, 0);
        }
    }

    // C/D layout: col = lane&15, row = quad*4 + reg (m89-verified)
    float* outp = (blockIdx.z == 0) ? out0 : out1;
    #pragma unroll
    for (int i = 0; i < 4; ++i) {
        #pragma unroll
        for (int r = 0; r < 4; ++r) {
            const int q = RM + wm + i * 16 + quad * 4 + r;
            #pragma unroll
            for (int j = 0; j < 2; ++j) {
                const int p = CN + wn + j * 16 + l15;
                outp[(size_t)q * GN + p] = acc[i][j][r];
            }
        }
    }
}

// ---------------------------------------------------------------------------
// Kernel 3: combine split-K partials + softbound epilogue.
// out = 4*w*(1-w) * A_SCALE * (P0 + P1); P0 aliases out (raw partial).
// ---------------------------------------------------------------------------
__global__ __launch_bounds__(256) void combine_kernel(
    const float4* __restrict__ W,
    const float4* __restrict__ P1,
    float4* __restrict__ out)
{
    const size_t i = (size_t)blockIdx.x * 256 + threadIdx.x;
    float4 w = W[i];
    float4 a = out[i];
    float4 b = P1[i];
    float4 o;
    o.x = 4.0f * w.x * (1.0f - w.x) * A_SCALE * (a.x + b.x);
    o.y = 4.0f * w.y * (1.0f - w.y) * A_SCALE * (a.y + b.y);
    o.z = 4.0f * w.z * (1.0f - w.z) * A_SCALE * (a.z + b.z);
    o.w = 4.0f * w.w * (1.0f - w.w) * A_SCALE * (a.w + b.w);
    out[i] = o;
}

extern "C" void kernel_launch(void* const* d_in, const int* in_sizes, int n_in,
                              void* d_out, int out_size, void* d_ws, size_t ws_size,
                              hipStream_t stream) {
    const float* W    = (const float*)d_in[0];  // [2048][2048]
    const float* pre  = (const float*)d_in[1];  // [16][128][2048]
    const float* post = (const float*)d_in[2];  // [16][128][2048]
    const int*   dt   = (const int*)d_in[3];
    float* out = (float*)d_out;

    __hip_bfloat16* AT = (__hip_bfloat16*)d_ws;            // 8 MB
    __hip_bfloat16* BT = AT + (size_t)GN * KTOT;           // +8 MB
    float* P1 = (float*)((char*)d_ws + (size_t)16 * 1024 * 1024);  // +16 MB (ws>=32MB; R5 ran with 48)

    trace_kernel<<<dim3(32, 16, 2), 256, 0, stream>>>(pre, post, dt, AT, BT);
    stdp_gemm<<<dim3(32, 16, 2), 256, 0, stream>>>(AT, BT, out, P1, KTOT / 2);
    combine_kernel<<<4096, 256, 0, stream>>>((const float4*)W, (const float4*)P1,
                                             (float4*)out);
}

// Round 7
// 123.198 us; speedup vs baseline: 1.9598x; 1.0444x over previous
//
#include <hip/hip_runtime.h>
#include <hip/hip_bf16.h>

// STDP via the antisymmetric-kernel identity (verified R6, absmax 9.8e-4):
//   out[q,p] = 4w(1-w) * A_SCALE * sum_{b,t} post_s[b,t,q] * Z[b,t,p]
//   Z = pre_tr - pre_rt;  tr = causal decay scan, rt = anti-causal scan
//   (rt[t] = decay*rt[t+1] + s[t] for t>=1, rt[0]=0).  K = B*T = 2048.
//   AT[q][b*128+t] = post_spikes (bf16);  BT[p][b*128+t] = Z (bf16, one round)

typedef __attribute__((ext_vector_type(8))) short bf16x8;
typedef __attribute__((ext_vector_type(4))) float f32x4;

#define GN 2048
#define KTOT 2048
#define A_SCALE (0.01f / 16.0f)
#define FST 68   // fbuf dword stride (16B-aligned float4 rows, 2-way-free scan reads)
#define ZST 66   // zbuf elem stride (8B-aligned packed writes)

#define GLOAD_LDS16(gp, lp) \
    __builtin_amdgcn_global_load_lds((const __attribute__((address_space(1))) void*)(gp), \
                                     (__attribute__((address_space(3))) void*)(lp), 16, 0, 0)

__device__ __forceinline__ unsigned bf16bits(float x) {
    __hip_bfloat16 h = __float2bfloat16(x);
    return (unsigned)*(unsigned short*)&h;
}

// ---------------------------------------------------------------------------
// Kernel 1: transpose (+ double scan for the pre side), float4 global loads.
// grid (32, 16, 2), block 256 (4 waves). z=0: post -> AT (spikes only),
// z=1: pre -> BT (Z = tr - rt, fp32 scans).  LDS 51.7 KB -> 3 blocks/CU.
// ---------------------------------------------------------------------------
__global__ __launch_bounds__(256) void trace_kernel(
    const float* __restrict__ pre,
    const float* __restrict__ post,
    const int* __restrict__ dtp,
    __hip_bfloat16* __restrict__ AT,
    __hip_bfloat16* __restrict__ BT)
{
    __shared__ float fbuf[128 * FST];                // 34816 B, t-major fp32
    __shared__ __hip_bfloat16 zbuf[128 * ZST];       // 16896 B, t-major bf16

    const int tid = threadIdx.x;
    const int w   = tid >> 6;    // wave 0..3
    const int l   = tid & 63;
    const int nq  = tid & 15;    // float4 group along n
    const int tl  = tid >> 4;    // t-row within a 16-row pass
    const int n0  = blockIdx.x * 64;
    const int b   = blockIdx.y;
    const int a   = blockIdx.z;  // 0: post->AT, 1: pre->BT

    int di = dtp[0];
    float dtf = (di > 0 && di < 1000000) ? (float)di : *(const float*)dtp;
    const float decay = __expf(-dtf / 20.0f);

    if (a == 0) {
        // spikes only: float4 load -> packed bf16x4 store
        #pragma unroll
        for (int pass = 0; pass < 8; ++pass) {
            const int t = pass * 16 + tl;
            float4 v = *(const float4*)&post[((size_t)b * 128 + t) * GN + n0 + 4 * nq];
            uint2 pk;
            pk.x = bf16bits(v.x) | (bf16bits(v.y) << 16);
            pk.y = bf16bits(v.z) | (bf16bits(v.w) << 16);
            *(uint2*)&zbuf[t * ZST + 4 * nq] = pk;
        }
        __syncthreads();
    } else {
        #pragma unroll
        for (int pass = 0; pass < 8; ++pass) {
            const int t = pass * 16 + tl;
            float4 v = *(const float4*)&pre[((size_t)b * 128 + t) * GN + n0 + 4 * nq];
            *(float4*)&fbuf[t * FST + 4 * nq] = v;
        }
        __syncthreads();

        const int t0 = 32 * w;   // this wave's t segment [t0, t0+32)
        // forward scan: tr[t] = decay*tr[t-1] + s[t] (t>=1), tr[0]=0
        float carry = 0.0f;
        #pragma unroll 8
        for (int t = 1; t < t0; ++t)
            carry = decay * carry + fbuf[t * FST + l];
        float z[32];
        #pragma unroll
        for (int j = 0; j < 32; ++j) {
            const int t = t0 + j;
            if (t >= 1) carry = decay * carry + fbuf[t * FST + l];
            z[j] = carry;                     // tr (t=0 -> 0)
        }
        // backward scan: rt[t] = decay*rt[t+1] + s[t]; subtract for t>=1
        float bc = 0.0f;
        #pragma unroll 8
        for (int t = 127; t >= t0 + 32; --t)
            bc = decay * bc + fbuf[t * FST + l];
        #pragma unroll
        for (int j = 31; j >= 0; --j) {
            const int t = t0 + j;
            bc = decay * bc + fbuf[t * FST + l];
            if (t >= 1) z[j] -= bc;           // Z = tr - rt   (Z[0] = 0)
        }
        #pragma unroll
        for (int j = 0; j < 32; ++j)
            zbuf[(t0 + j) * ZST + l] = __float2bfloat16(z[j]);
        __syncthreads();
    }

    // transpose-write: 1024 16B-chunks/block, 4 per thread, coalesced.
    __hip_bfloat16* dst = (a == 0) ? AT : BT;
    #pragma unroll
    for (int j = 0; j < 4; ++j) {
        const int c  = tid + 256 * j;   // 0..1023
        const int n  = c >> 4;          // 0..63
        const int tc = c & 15;          // 8-t chunk
        unsigned int vv[8];
        #pragma unroll
        for (int i = 0; i < 8; ++i)
            vv[i] = *(const unsigned short*)&zbuf[(8 * tc + i) * ZST + n];
        uint4 pk;
        pk.x = vv[0] | (vv[1] << 16);
        pk.y = vv[2] | (vv[3] << 16);
        pk.z = vv[4] | (vv[5] << 16);
        pk.w = vv[6] | (vv[7] << 16);
        *(uint4*)(dst + (size_t)(n0 + n) * KTOT + b * 128 + tc * 8) = pk;
    }
}

// ---------------------------------------------------------------------------
// Kernel 2: out = 4w(1-w)*A_SCALE * (AT * BT^T), full K=2048, fused epilogue.
// 64x64 tile -> grid (32,32) = 1024 blocks = 4 blocks/CU (the R5-proven
// m114-overlap regime) with NO split-K: no partial traffic, no combine
// kernel (-64 MB HBM, -1 launch).  BK=64, single-buffer global_load_lds,
// XOR k-chunk swizzle on the source pointer.  4 waves of 32x32: acc[2][2].
// LDS 16 KB, VGPR ~50 -> occupancy >= R6.  A/B re-reads are LLC-served
// (16 MB working set; ~20 TB/s < 34.5 TB/s L2 ceiling).
// ---------------------------------------------------------------------------
__global__ __launch_bounds__(256) void stdp_gemm(
    const __hip_bfloat16* __restrict__ AT,
    const __hip_bfloat16* __restrict__ BT,
    const float* __restrict__ W,
    float* __restrict__ out)
{
    __shared__ alignas(16) __hip_bfloat16 As[64 * 64];
    __shared__ alignas(16) __hip_bfloat16 Bs[64 * 64];

    const int tid  = threadIdx.x;
    const int lane = tid & 63;
    const int wv   = tid >> 6;          // wave 0..3
    const int wm   = (wv >> 1) * 32;    // {0,32}
    const int wn   = (wv & 1) * 32;     // {0,32}
    const int RM   = blockIdx.y * 64;   // q base
    const int CN   = blockIdx.x * 64;   // p base
    const int l15  = lane & 15;
    const int quad = lane >> 4;

    f32x4 acc[2][2] = {};

    for (int k0 = 0; k0 < KTOT; k0 += 64) {
        __syncthreads();  // previous iter's ds_reads done before overwrite
        #pragma unroll
        for (int it = 0; it < 2; ++it) {
            const int cbase = it * 256 + wv * 64;      // wave-uniform chunk base
            const int c     = cbase + lane;            // 16B chunk id 0..511
            const int row   = c >> 3;                  // 0..63
            const int kc    = (c & 7) ^ (row & 7);     // XOR swizzle (self-inverse)
            GLOAD_LDS16(AT + (size_t)(RM + row) * KTOT + k0 + kc * 8, As + (size_t)cbase * 8);
            GLOAD_LDS16(BT + (size_t)(CN + row) * KTOT + k0 + kc * 8, Bs + (size_t)cbase * 8);
        }
        __syncthreads();  // vmcnt(0) drain: staged data visible

        #pragma unroll
        for (int kk = 0; kk < 64; kk += 32) {
            const int jg = (kk >> 3) + quad;           // k-chunk 0..3 / 4..7
            bf16x8 af[2], bfr[2];
            #pragma unroll
            for (int i = 0; i < 2; ++i) {
                const int mr = wm + i * 16 + l15;
                af[i] = *(const bf16x8*)(As + mr * 64 + ((jg ^ (mr & 7)) * 8));
                const int nr = wn + i * 16 + l15;
                bfr[i] = *(const bf16x8*)(Bs + nr * 64 + ((jg ^ (nr & 7)) * 8));
            }
            #pragma unroll
            for (int i = 0; i < 2; ++i)
                #pragma unroll
                for (int j = 0; j < 2; ++j)
                    acc[i][j] = __builtin_amdgcn_mfma_f32_16x16x32_bf16(
                        af[i], bfr[j], acc[i][j], 0, 0, 0);
        }
    }

    // fused epilogue: C/D layout col = lane&15, row = quad*4 + reg (m89)
    #pragma unroll
    for (int i = 0; i < 2; ++i) {
        #pragma unroll
        for (int r = 0; r < 4; ++r) {
            const int q = RM + wm + i * 16 + quad * 4 + r;
            #pragma unroll
            for (int j = 0; j < 2; ++j) {
                const int p = CN + wn + j * 16 + l15;
                const float w  = W[(size_t)q * GN + p];
                const float wf = 4.0f * w * (1.0f - w);
                out[(size_t)q * GN + p] = wf * A_SCALE * acc[i][j][r];
            }
        }
    }
}

extern "C" void kernel_launch(void* const* d_in, const int* in_sizes, int n_in,
                              void* d_out, int out_size, void* d_ws, size_t ws_size,
                              hipStream_t stream) {
    const float* W    = (const float*)d_in[0];  // [2048][2048]
    const float* pre  = (const float*)d_in[1];  // [16][128][2048]
    const float* post = (const float*)d_in[2];  // [16][128][2048]
    const int*   dt   = (const int*)d_in[3];
    float* out = (float*)d_out;

    __hip_bfloat16* AT = (__hip_bfloat16*)d_ws;            // 8 MB
    __hip_bfloat16* BT = AT + (size_t)GN * KTOT;           // +8 MB

    trace_kernel<<<dim3(32, 16, 2), 256, 0, stream>>>(pre, post, dt, AT, BT);
    stdp_gemm<<<dim3(32, 32), 256, 0, stream>>>(AT, BT, W, out);
}